// Round 7
// baseline (746.822 us; speedup 1.0000x reference)
//
#include <hip/hip_runtime.h>
#include <hip/hip_bf16.h>
#include <hip/hip_cooperative_groups.h>
#include <math.h>

namespace cg = cooperative_groups;

// ---------------------------------------------------------------------------
// GCN: 3x GCNConv(128->128) + fused (Wp1@Wp2) head + log_softmax.
// Round 18: prep chain fused into ONE cooperative kernel:
//   phase A scatter (782 blk x 2048 edges) -> grid.sync ->
//   phase B degfill (block b = bucket b)   -> grid.sync ->
//   phase C deg_scatter || weight-prep (disjoint block ranges).
// Removes 2 kernel-boundary drains + launches; scatter parallelism 2x.
// LDS phases overlaid in a 16KB union -> 8 blocks/CU -> coop capacity 2048.
// __threadfence before each grid.sync for cross-XCD visibility (all arrays
// are first-read-after-sync, so no stale reader lines).
// Runtime fallback to 3 ordinary launches if coop launch is rejected.
// agg/gather/gemm unchanged from R6 (agg at compulsory-traffic wall:
// FETCH ~191MB = per-XCD unique-row floor, fill pinned ~2.8 TB/s).
// ---------------------------------------------------------------------------

#define DH 128     // feature dim (D == H == 128)
#define NC 40      // classes
#define BN 128     // nodes per bucket
#define MAXNB 1024 // max buckets (N <= 131072)
#define CAP 2560   // edge capacity per bucket (mean 2048, +11 sigma)
#define SP 136     // LDS row stride (elems): 128 + 8 pad
#define NPREP (3 * DH * DH + 48 * DH + 48)

typedef __attribute__((ext_vector_type(8))) short bf16x8;
typedef __attribute__((ext_vector_type(4))) float f32x4;

__device__ __forceinline__ unsigned short f2bf(float f) {
    unsigned u = __float_as_uint(f);
    unsigned r = (u + 0x7fffu + ((u >> 16) & 1u)) >> 16;   // RNE
    return (unsigned short)r;
}
__device__ __forceinline__ unsigned pack2(float lo, float hi) {
    return (unsigned)f2bf(lo) | ((unsigned)f2bf(hi) << 16);
}

// ---------------- shared-memory overlays ------------------------------------

struct SmA { unsigned hist[MAXNB], gbase[MAXNB], lim[MAXNB], cur[MAXNB]; };        // 16 KB
struct SmB { int lcsr[CAP]; unsigned h[BN], lb[BN], cur[BN], dhh[256], tot; };     // ~12.8 KB
struct SmC { unsigned hh[256], base[256], cur[256], sdh[256], sns[256]; };         // 5 KB
union SMU { SmA a; SmB b; SmC c; };

// ---------------- phase bodies (shared between coop kernel and fallback) ----

__device__ __forceinline__ void scatter_body(const int* __restrict__ src,
                                             const int* __restrict__ dst,
                                             int e0, int nE,
                                             unsigned* __restrict__ bpos,
                                             unsigned* __restrict__ ebuf,
                                             SmA* sm) {
    const int tid = threadIdx.x;
    for (int i = tid; i < MAXNB; i += 256) { sm->hist[i] = 0; sm->cur[i] = 0; }
    __syncthreads();
    const int nE4 = (nE > 0) ? (nE & ~3) : 0;
    for (int i = tid * 4; i < nE4; i += 1024) {
        int4 dv = *(const int4*)(dst + e0 + i);
        atomicAdd(&sm->hist[(unsigned)dv.x >> 7], 1u);
        atomicAdd(&sm->hist[(unsigned)dv.y >> 7], 1u);
        atomicAdd(&sm->hist[(unsigned)dv.z >> 7], 1u);
        atomicAdd(&sm->hist[(unsigned)dv.w >> 7], 1u);
    }
    for (int i = nE4 + tid; i < nE; i += 256)
        atomicAdd(&sm->hist[(unsigned)dst[e0 + i] >> 7], 1u);
    __syncthreads();
    for (int i = tid; i < MAXNB; i += 256) {
        unsigned h = sm->hist[i];
        if (h) {
            unsigned o = (unsigned)i * CAP + atomicAdd(&bpos[i], h);
            sm->gbase[i] = o;
            sm->lim[i] = min(o + h, (unsigned)(i + 1) * CAP);
        }
    }
    __syncthreads();
    for (int i = tid * 4; i < nE4; i += 1024) {
        int4 sv = *(const int4*)(src + e0 + i);
        int4 dv = *(const int4*)(dst + e0 + i);
        {
            unsigned b = (unsigned)dv.x >> 7;
            unsigned p = sm->gbase[b] + atomicAdd(&sm->cur[b], 1u);
            if (p < sm->lim[b]) ebuf[p] = ((unsigned)sv.x << 7) | ((unsigned)dv.x & 127u);
        }
        {
            unsigned b = (unsigned)dv.y >> 7;
            unsigned p = sm->gbase[b] + atomicAdd(&sm->cur[b], 1u);
            if (p < sm->lim[b]) ebuf[p] = ((unsigned)sv.y << 7) | ((unsigned)dv.y & 127u);
        }
        {
            unsigned b = (unsigned)dv.z >> 7;
            unsigned p = sm->gbase[b] + atomicAdd(&sm->cur[b], 1u);
            if (p < sm->lim[b]) ebuf[p] = ((unsigned)sv.z << 7) | ((unsigned)dv.z & 127u);
        }
        {
            unsigned b = (unsigned)dv.w >> 7;
            unsigned p = sm->gbase[b] + atomicAdd(&sm->cur[b], 1u);
            if (p < sm->lim[b]) ebuf[p] = ((unsigned)sv.w << 7) | ((unsigned)dv.w & 127u);
        }
    }
    for (int i = nE4 + tid; i < nE; i += 256) {
        int s = src[e0 + i];
        int d = dst[e0 + i];
        unsigned b = (unsigned)d >> 7;
        unsigned p = sm->gbase[b] + atomicAdd(&sm->cur[b], 1u);
        if (p < sm->lim[b]) ebuf[p] = ((unsigned)s << 7) | ((unsigned)d & 127u);
    }
}

__device__ __forceinline__ void degfill_body(int b,
                                             const unsigned* __restrict__ ebuf,
                                             const unsigned* __restrict__ bpos,
                                             unsigned* __restrict__ cnt,
                                             float* __restrict__ nrm,
                                             unsigned* __restrict__ offN,
                                             unsigned* __restrict__ dh,
                                             int* __restrict__ csr, int N,
                                             SmB* sm) {
    const int tid = threadIdx.x;
    unsigned ebase = (unsigned)b * CAP;
    unsigned used = min(bpos[b], (unsigned)CAP);
    unsigned used4 = used & ~3u;

    if (tid < BN) { sm->h[tid] = 0; sm->cur[tid] = 0; }
    sm->dhh[tid] = 0;
    if (tid == 0) sm->tot = 0;
    __syncthreads();

    for (unsigned i = tid * 4; i < used4; i += 1024) {
        uint4 v = *(const uint4*)(ebuf + ebase + i);
        atomicAdd(&sm->h[v.x & 127u], 1u);
        atomicAdd(&sm->h[v.y & 127u], 1u);
        atomicAdd(&sm->h[v.z & 127u], 1u);
        atomicAdd(&sm->h[v.w & 127u], 1u);
    }
    for (unsigned i = used4 + tid; i < used; i += 256)
        atomicAdd(&sm->h[ebuf[ebase + i] & 127u], 1u);
    __syncthreads();

    if (tid < BN) {
        unsigned m = sm->h[tid];
        sm->lb[tid] = m ? atomicAdd(&sm->tot, m) : 0u;
    }
    __syncthreads();

    for (unsigned i = tid * 4; i < used4; i += 1024) {
        uint4 v = *(const uint4*)(ebuf + ebase + i);
        {
            unsigned nl = v.x & 127u;
            unsigned r = atomicAdd(&sm->cur[nl], 1u);
            sm->lcsr[sm->lb[nl] + r] = (int)(v.x >> 7);
        }
        {
            unsigned nl = v.y & 127u;
            unsigned r = atomicAdd(&sm->cur[nl], 1u);
            sm->lcsr[sm->lb[nl] + r] = (int)(v.y >> 7);
        }
        {
            unsigned nl = v.z & 127u;
            unsigned r = atomicAdd(&sm->cur[nl], 1u);
            sm->lcsr[sm->lb[nl] + r] = (int)(v.z >> 7);
        }
        {
            unsigned nl = v.w & 127u;
            unsigned r = atomicAdd(&sm->cur[nl], 1u);
            sm->lcsr[sm->lb[nl] + r] = (int)(v.w >> 7);
        }
    }
    for (unsigned i = used4 + tid; i < used; i += 256) {
        unsigned v = ebuf[ebase + i];
        unsigned nl = v & 127u;
        unsigned r = atomicAdd(&sm->cur[nl], 1u);
        sm->lcsr[sm->lb[nl] + r] = (int)(v >> 7);
    }

    if (tid < BN) {
        int node = b * BN + tid;
        if (node < N) {
            unsigned m = sm->h[tid];
            cnt[node] = m;
            nrm[node] = rsqrtf((float)m + 1.0f);
            offN[node] = ebase + sm->lb[tid];
            atomicAdd(&sm->dhh[min(m, 255u)], 1u);
        }
    }
    __syncthreads();

    for (unsigned i = tid * 4; i < used4; i += 1024)
        *(int4*)(csr + ebase + i) = *(const int4*)&sm->lcsr[i];
    for (unsigned i = used4 + tid; i < used; i += 256)
        csr[ebase + i] = sm->lcsr[i];
    if (sm->dhh[tid]) atomicAdd(&dh[tid], sm->dhh[tid]);
}

__device__ __forceinline__ void degscatter_body(int chunk,
                                                const unsigned* __restrict__ cnt, int N,
                                                const unsigned* __restrict__ dh,
                                                unsigned* __restrict__ binpos,
                                                const unsigned* __restrict__ offN,
                                                int* __restrict__ perm,
                                                unsigned* __restrict__ pd2,
                                                SmC* sm) {
    int t = threadIdx.x;
    sm->hh[t] = 0; sm->cur[t] = 0; sm->sdh[t] = dh[t];
    __syncthreads();
    unsigned ns = 0;
    for (int d = t + 1; d < 256; ++d) ns += sm->sdh[d];
    sm->sns[t] = ns;
    int i = chunk * 256 + t;
    unsigned d = 0;
    if (i < N) { d = min(cnt[i], 255u); atomicAdd(&sm->hh[d], 1u); }
    __syncthreads();
    if (sm->hh[t]) sm->base[t] = sm->sns[t] + atomicAdd(&binpos[t], sm->hh[t]);
    __syncthreads();
    if (i < N) {
        unsigned r = atomicAdd(&sm->cur[d], 1u);
        unsigned idx = sm->base[d] + r;
        perm[idx] = i;
        pd2[idx] = (offN[i] << 9) | min(cnt[i], 511u);
    }
}

__device__ __forceinline__ void weightprep_body(int id,
        const float* __restrict__ W1, const float* __restrict__ W2,
        const float* __restrict__ W3, const float* __restrict__ Wp1,
        const float* __restrict__ bp1, const float* __restrict__ Wp2,
        const float* __restrict__ bp2, unsigned short* __restrict__ Wt,
        unsigned short* __restrict__ Wft, float* __restrict__ bfh) {
    if (id < 3 * DH * DH) {
        int l = id >> 14, r = id & (DH * DH - 1);
        int k = r >> 7, n = r & 127;
        const float* W = (l == 0) ? W1 : (l == 1) ? W2 : W3;
        Wt[l * DH * DH + n * DH + k] = f2bf(W[k * DH + n]);
    } else if (id < 3 * DH * DH + 48 * DH) {
        int o = id - 3 * DH * DH;
        int c = o >> 7, k = o & 127;
        float acc = 0.f;
        if (c < NC)
            for (int j = 0; j < DH; ++j) acc += Wp1[k * DH + j] * Wp2[j * NC + c];
        Wft[c * DH + k] = f2bf(acc);
    } else if (id < NPREP) {
        int c = id - 3 * DH * DH - 48 * DH;
        float acc = 0.f;
        if (c < NC) {
            acc = bp2[c];
            for (int j = 0; j < DH; ++j) acc += bp1[j] * Wp2[j * NC + c];
        }
        bfh[c] = acc;
    }
}

// ---------------- cooperative fused prep ------------------------------------

__global__ __launch_bounds__(256) void prep_fused(
        const int* __restrict__ src, const int* __restrict__ dst, int E,
        unsigned* __restrict__ bpos, unsigned* __restrict__ ebuf,
        unsigned* __restrict__ cnt, float* __restrict__ nrm,
        unsigned* __restrict__ offN, unsigned* __restrict__ dh,
        int* __restrict__ csr, int N,
        unsigned* __restrict__ binpos, int* __restrict__ perm,
        unsigned* __restrict__ pd2,
        const float* __restrict__ W1, const float* __restrict__ W2,
        const float* __restrict__ W3, const float* __restrict__ Wp1,
        const float* __restrict__ bp1, const float* __restrict__ Wp2,
        const float* __restrict__ bp2, unsigned short* __restrict__ Wt,
        unsigned short* __restrict__ Wft, float* __restrict__ bfh,
        int NB, int gN, int CHA) {
    __shared__ SMU sm;
    cg::grid_group grid = cg::this_grid();
    const int bid = blockIdx.x;

    // phase A: scatter
    {
        int e0 = bid * CHA;
        int nE = min(CHA, E - e0);
        scatter_body(src, dst, e0, nE, bpos, ebuf, &sm.a);
    }
    __threadfence();
    grid.sync();

    // phase B: degfill (block b = bucket b)
    if (bid < NB)
        degfill_body(bid, ebuf, bpos, cnt, nrm, offN, dh, csr, N, &sm.b);
    __threadfence();
    grid.sync();

    // phase C: deg_scatter || weight prep (disjoint block ranges)
    if (bid < gN)
        degscatter_body(bid, cnt, N, dh, binpos, offN, perm, pd2, &sm.c);
    else
        weightprep_body((bid - gN) * 256 + (int)threadIdx.x,
                        W1, W2, W3, Wp1, bp1, Wp2, bp2, Wt, Wft, bfh);
}

// ---------------- fallback (ordinary launches) ------------------------------

__global__ __launch_bounds__(256) void k_scatter_prep(
        const int* __restrict__ src, const int* __restrict__ dst, int E,
        unsigned* __restrict__ bpos, unsigned* __restrict__ ebuf,
        const float* __restrict__ W1, const float* __restrict__ W2,
        const float* __restrict__ W3, const float* __restrict__ Wp1,
        const float* __restrict__ bp1, const float* __restrict__ Wp2,
        const float* __restrict__ bp2, unsigned short* __restrict__ Wt,
        unsigned short* __restrict__ Wft, float* __restrict__ bfh,
        int gC, int CHA) {
    __shared__ SmA a;
    if (blockIdx.x >= gC) {
        weightprep_body((blockIdx.x - gC) * 256 + (int)threadIdx.x,
                        W1, W2, W3, Wp1, bp1, Wp2, bp2, Wt, Wft, bfh);
        return;
    }
    int e0 = blockIdx.x * CHA;
    int nE = min(CHA, E - e0);
    scatter_body(src, dst, e0, nE, bpos, ebuf, &a);
}

__global__ __launch_bounds__(256) void k_degfill(const unsigned* __restrict__ ebuf,
                                                 const unsigned* __restrict__ bpos,
                                                 unsigned* __restrict__ cnt,
                                                 float* __restrict__ nrm,
                                                 unsigned* __restrict__ offN,
                                                 unsigned* __restrict__ dh,
                                                 int* __restrict__ csr, int N) {
    __shared__ SmB b;
    degfill_body(blockIdx.x, ebuf, bpos, cnt, nrm, offN, dh, csr, N, &b);
}

__global__ __launch_bounds__(256) void k_degscatter(const unsigned* __restrict__ cnt, int N,
                                                    const unsigned* __restrict__ dh,
                                                    unsigned* __restrict__ binpos,
                                                    const unsigned* __restrict__ offN,
                                                    int* __restrict__ perm,
                                                    unsigned* __restrict__ pd2) {
    __shared__ SmC c;
    degscatter_body(blockIdx.x, cnt, N, dh, binpos, offN, perm, pd2, &c);
}

// ---------------- layer-1 MFMA GEMM: Ab = bf16(nrm * (x_f32 @ W1)) ----------

__global__ __launch_bounds__(256) void gemm_mfma_f32(const float* __restrict__ X,
                                                     const unsigned short* __restrict__ Wt,
                                                     const float* __restrict__ nrm,
                                                     unsigned short* __restrict__ outb,
                                                     int nrows) {
    const int tid = threadIdx.x;
    const int wave = tid >> 6;
    const int lane = tid & 63;
    const int m = lane & 15;
    const int quad = lane >> 4;
    const int rbase = blockIdx.x * 64 + wave * 16;

    union U8 { bf16x8 v; unsigned u[4]; };

    f32x4 acc[8];
#pragma unroll
    for (int ct = 0; ct < 8; ++ct) acc[ct] = (f32x4){0.f, 0.f, 0.f, 0.f};

#pragma unroll
    for (int kt = 0; kt < 4; ++kt) {
        const int kof = kt * 32 + quad * 8;
        int r = rbase + m;
        r = (r < nrows) ? r : (nrows - 1);
        const float* p = X + (size_t)r * DH + kof;
        float4 u0 = *(const float4*)p;
        float4 u1 = *(const float4*)(p + 4);
        U8 t;
        t.u[0] = pack2(u0.x, u0.y);
        t.u[1] = pack2(u0.z, u0.w);
        t.u[2] = pack2(u1.x, u1.y);
        t.u[3] = pack2(u1.z, u1.w);
        bf16x8 a = t.v;
        bf16x8 b[8];
#pragma unroll
        for (int ct = 0; ct < 8; ++ct)
            b[ct] = *(const bf16x8*)(Wt + (ct * 16 + m) * DH + kof);
#pragma unroll
        for (int ct = 0; ct < 8; ++ct)
            acc[ct] = __builtin_amdgcn_mfma_f32_16x16x32_bf16(a, b[ct], acc[ct], 0, 0, 0);
    }

#pragma unroll
    for (int reg = 0; reg < 4; ++reg) {
        int r = rbase + quad * 4 + reg;
        if (r < nrows) {
            float s = nrm[r];
#pragma unroll
            for (int ct = 0; ct < 8; ++ct)
                outb[(size_t)r * DH + ct * 16 + m] = f2bf(acc[ct][reg] * s);
        }
    }
}

// ---------------- gather phase (perm order) ---------------------------------

__device__ __forceinline__ void bf8_add(float* acc, uint4 v) {
    acc[0] += __uint_as_float(v.x << 16);
    acc[1] += __uint_as_float(v.x & 0xffff0000u);
    acc[2] += __uint_as_float(v.y << 16);
    acc[3] += __uint_as_float(v.y & 0xffff0000u);
    acc[4] += __uint_as_float(v.z << 16);
    acc[5] += __uint_as_float(v.z & 0xffff0000u);
    acc[6] += __uint_as_float(v.w << 16);
    acc[7] += __uint_as_float(v.w & 0xffff0000u);
}

__device__ __forceinline__ void gather_phase(const uint4* __restrict__ Abf,
                                             const int* __restrict__ csr,
                                             const unsigned* __restrict__ pd2,
                                             const int* __restrict__ perm,
                                             const float* __restrict__ bias,
                                             unsigned short (*sA)[SP],
                                             int* snode, float* snrm, int N) {
    const int tid = threadIdx.x;
    const int g = tid >> 4;
    const int lane = tid & 15;
    const int idx = blockIdx.x * 16 + g;
    if (idx < N) {
        const unsigned pd = pd2[idx];
        const unsigned o = pd >> 9;
        const unsigned d = pd & 511u;
        const int node = perm[idx];

        // up-front csr prefetch: lane-distributed, covers e < 64
        int i0 = 0, i1 = 0, i2 = 0, i3 = 0;
        if ((unsigned)lane < d)        i0 = csr[o + lane];
        if ((unsigned)(16 + lane) < d) i1 = csr[o + 16 + lane];
        if ((unsigned)(32 + lane) < d) i2 = csr[o + 32 + lane];
        if ((unsigned)(48 + lane) < d) i3 = csr[o + 48 + lane];

        float acc[8];
        {
            uint4 v = Abf[(size_t)node * 16 + lane];   // self term
            acc[0] = __uint_as_float(v.x << 16);
            acc[1] = __uint_as_float(v.x & 0xffff0000u);
            acc[2] = __uint_as_float(v.y << 16);
            acc[3] = __uint_as_float(v.y & 0xffff0000u);
            acc[4] = __uint_as_float(v.z << 16);
            acc[5] = __uint_as_float(v.z & 0xffff0000u);
            acc[6] = __uint_as_float(v.w << 16);
            acc[7] = __uint_as_float(v.w & 0xffff0000u);
        }

        const unsigned dl = min(d, 64u);
        const int sb = g << 4;
        unsigned e = 0;
        for (; e + 4 <= dl; e += 4) {
            int rsel = (e < 16) ? i0 : (e < 32) ? i1 : (e < 48) ? i2 : i3;
            int bb = sb + (int)(e & 15u);
            int s0 = __shfl(rsel, bb + 0);
            int s1 = __shfl(rsel, bb + 1);
            int s2 = __shfl(rsel, bb + 2);
            int s3 = __shfl(rsel, bb + 3);
            uint4 v0 = Abf[(size_t)s0 * 16 + lane];
            uint4 v1 = Abf[(size_t)s1 * 16 + lane];
            uint4 v2 = Abf[(size_t)s2 * 16 + lane];
            uint4 v3 = Abf[(size_t)s3 * 16 + lane];
            bf8_add(acc, v0);
            bf8_add(acc, v1);
            bf8_add(acc, v2);
            bf8_add(acc, v3);
        }
        for (; e < dl; ++e) {
            int rsel = (e < 16) ? i0 : (e < 32) ? i1 : (e < 48) ? i2 : i3;
            int s = __shfl(rsel, sb + (int)(e & 15u));
            uint4 v = Abf[(size_t)s * 16 + lane];
            bf8_add(acc, v);
        }
        for (; e < d; ++e) {                     // d > 64 spill (P ~ 0)
            int s = csr[o + e];
            uint4 v = Abf[(size_t)s * 16 + lane];
            bf8_add(acc, v);
        }

        float nm = rsqrtf((float)d + 1.0f);
        if (lane == 0) { snode[g] = node; snrm[g] = nm; }
        float4 b0 = *(const float4*)(bias + lane * 8);
        float4 b1 = *(const float4*)(bias + lane * 8 + 4);
        uint4 ov;
        ov.x = pack2(fmaxf(acc[0] * nm + b0.x, 0.f), fmaxf(acc[1] * nm + b0.y, 0.f));
        ov.y = pack2(fmaxf(acc[2] * nm + b0.z, 0.f), fmaxf(acc[3] * nm + b0.w, 0.f));
        ov.z = pack2(fmaxf(acc[4] * nm + b1.x, 0.f), fmaxf(acc[5] * nm + b1.y, 0.f));
        ov.w = pack2(fmaxf(acc[6] * nm + b1.z, 0.f), fmaxf(acc[7] * nm + b1.w, 0.f));
        *(uint4*)&sA[g][lane * 8] = ov;
    }
    __syncthreads();
}

// ---------------- fused: aggregate + next-layer GEMM ------------------------

__global__ __launch_bounds__(256) void agg_gemm(const uint4* __restrict__ Abf,
                                                const int* __restrict__ csr,
                                                const unsigned* __restrict__ pd2,
                                                const int* __restrict__ perm,
                                                const float* __restrict__ bias,
                                                const unsigned short* __restrict__ Wt,
                                                unsigned short* __restrict__ outb, int N) {
    __shared__ unsigned short sA[16][SP];
    __shared__ int snode[16];
    __shared__ float snrm[16];
    gather_phase(Abf, csr, pd2, perm, bias, sA, snode, snrm, N);

    const int tid = threadIdx.x;
    const int wave = tid >> 6;
    const int l64 = tid & 63;
    const int m = l64 & 15;
    const int quad = l64 >> 4;

    f32x4 acc[2];
    acc[0] = (f32x4){0.f, 0.f, 0.f, 0.f};
    acc[1] = (f32x4){0.f, 0.f, 0.f, 0.f};

#pragma unroll
    for (int kt = 0; kt < 4; ++kt) {
        const int kof = kt * 32 + quad * 8;
        bf16x8 a = *(const bf16x8*)&sA[m][kof];
#pragma unroll
        for (int c2 = 0; c2 < 2; ++c2) {
            const int ct = wave * 2 + c2;
            bf16x8 b = *(const bf16x8*)(Wt + (ct * 16 + m) * DH + kof);
            acc[c2] = __builtin_amdgcn_mfma_f32_16x16x32_bf16(a, b, acc[c2], 0, 0, 0);
        }
    }

#pragma unroll
    for (int reg = 0; reg < 4; ++reg) {
        int idx = blockIdx.x * 16 + quad * 4 + reg;
        if (idx < N) {
            int r = snode[quad * 4 + reg];
            float s = snrm[quad * 4 + reg];
#pragma unroll
            for (int c2 = 0; c2 < 2; ++c2)
                outb[(size_t)r * DH + (wave * 2 + c2) * 16 + m] = f2bf(acc[c2][reg] * s);
        }
    }
}

// ---------------- fused: aggregate + head GEMM + log_softmax ----------------

__global__ __launch_bounds__(256) void agg_head(const uint4* __restrict__ Abf,
                                                const int* __restrict__ csr,
                                                const unsigned* __restrict__ pd2,
                                                const int* __restrict__ perm,
                                                const float* __restrict__ bias,
                                                const unsigned short* __restrict__ Wft,
                                                const float* __restrict__ bfh,
                                                float* __restrict__ out, int N) {
    __shared__ unsigned short sA[16][SP];
    __shared__ int snode[16];
    __shared__ float snrm[16];
    gather_phase(Abf, csr, pd2, perm, bias, sA, snode, snrm, N);

    const int tid = threadIdx.x;
    if (tid >= 64) return;                 // one wave does the 16x48 head
    const int m = tid & 15;
    const int quad = tid >> 4;

    f32x4 acc[3];
#pragma unroll
    for (int ct = 0; ct < 3; ++ct) acc[ct] = (f32x4){0.f, 0.f, 0.f, 0.f};

#pragma unroll
    for (int kt = 0; kt < 4; ++kt) {
        const int kof = kt * 32 + quad * 8;
        bf16x8 a = *(const bf16x8*)&sA[m][kof];
#pragma unroll
        for (int ct = 0; ct < 3; ++ct) {
            bf16x8 b = *(const bf16x8*)(Wft + (ct * 16 + m) * DH + kof);
            acc[ct] = __builtin_amdgcn_mfma_f32_16x16x32_bf16(a, b, acc[ct], 0, 0, 0);
        }
    }

    float bias0 = bfh[m];
    float bias1 = bfh[16 + m];
    float bias2 = bfh[32 + m];

#pragma unroll
    for (int reg = 0; reg < 4; ++reg) {
        float v0 = acc[0][reg] + bias0;
        float v1 = acc[1][reg] + bias1;
        float v2 = (m < 8) ? (acc[2][reg] + bias2) : -1e30f;
        float mx = fmaxf(fmaxf(v0, v1), v2);
#pragma unroll
        for (int dlt = 1; dlt < 16; dlt <<= 1) mx = fmaxf(mx, __shfl_xor(mx, dlt));
        float s = __expf(v0 - mx) + __expf(v1 - mx) + ((m < 8) ? __expf(v2 - mx) : 0.f);
#pragma unroll
        for (int dlt = 1; dlt < 16; dlt <<= 1) s += __shfl_xor(s, dlt);
        float ls = mx + __logf(s);
        int idx = blockIdx.x * 16 + quad * 4 + reg;
        if (idx < N) {
            int r = snode[quad * 4 + reg];
            out[(size_t)r * NC + m] = v0 - ls;
            out[(size_t)r * NC + 16 + m] = v1 - ls;
            if (m < 8) out[(size_t)r * NC + 32 + m] = v2 - ls;
        }
    }
}

// ---------------------------------------------------------------------------

extern "C" void kernel_launch(void* const* d_in, const int* in_sizes, int n_in,
                              void* d_out, int out_size, void* d_ws, size_t ws_size,
                              hipStream_t stream) {
    const float* x   = (const float*)d_in[0];
    const int*   ei  = (const int*)d_in[1];
    const float* W1  = (const float*)d_in[2];
    const float* b1  = (const float*)d_in[3];
    const float* W2  = (const float*)d_in[4];
    const float* b2  = (const float*)d_in[5];
    const float* W3  = (const float*)d_in[6];
    const float* b3  = (const float*)d_in[7];
    const float* Wp1 = (const float*)d_in[8];
    const float* bp1 = (const float*)d_in[9];
    const float* Wp2 = (const float*)d_in[10];
    const float* bp2 = (const float*)d_in[11];
    float* out = (float*)d_out;

    int N = in_sizes[0] / DH;
    int E = in_sizes[1] / 2;
    const int* src = ei;
    const int* dst = ei + E;
    int NB = (N + BN - 1) / BN;

    // workspace carve (all 16B aligned)
    char* w = (char*)d_ws;
    unsigned short* Ab  = (unsigned short*)w; w += (size_t)N * DH * 2;
    unsigned short* Bb  = (unsigned short*)w; w += (size_t)N * DH * 2;
    int*      csr    = (int*)w;      w += (size_t)NB * CAP * 4;
    unsigned* ebuf   = (unsigned*)w; w += (size_t)NB * CAP * 4;
    // ---- zeroed region (one memset): dh + binpos + bpos ----
    unsigned* dh     = (unsigned*)w; w += 256 * 4;
    unsigned* binpos = (unsigned*)w; w += 256 * 4;
    unsigned* bpos   = (unsigned*)w; w += MAXNB * 4;
    // ---- end zeroed region ----
    unsigned* cnt    = (unsigned*)w; w += (size_t)N * 4;
    float*    nrm    = (float*)w;    w += (size_t)N * 4;
    unsigned* offN   = (unsigned*)w; w += (size_t)N * 4;
    unsigned* pd2    = (unsigned*)w; w += (size_t)((N + 31) & ~31) * 4;
    int*      perm   = (int*)w;      w += (size_t)((N + 31) & ~31) * 4;
    unsigned short* Wt  = (unsigned short*)w; w += 3 * DH * DH * 2;
    unsigned short* Wft = (unsigned short*)w; w += 48 * DH * 2;
    float*    bfh    = (float*)w;    w += 64 * 4;

    int gN = (N + 255) / 256;
    int gP = (NPREP + 255) / 256;
    int NBg = NB;
    if (NBg < gN + gP) NBg = gN + gP;
    int CHA = (((E + NBg - 1) / NBg) + 3) & ~3;

    hipMemsetAsync(dh, 0, 256 * 4 + 256 * 4 + MAXNB * 4, stream);

    void* ka[] = {
        (void*)&src, (void*)&dst, (void*)&E, (void*)&bpos, (void*)&ebuf,
        (void*)&cnt, (void*)&nrm, (void*)&offN, (void*)&dh, (void*)&csr,
        (void*)&N, (void*)&binpos, (void*)&perm, (void*)&pd2,
        (void*)&W1, (void*)&W2, (void*)&W3, (void*)&Wp1, (void*)&bp1,
        (void*)&Wp2, (void*)&bp2, (void*)&Wt, (void*)&Wft, (void*)&bfh,
        (void*)&NB, (void*)&gN, (void*)&CHA
    };
    hipError_t ce = hipLaunchCooperativeKernel((void*)prep_fused, dim3(NBg), dim3(256),
                                               ka, 0, stream);
    if (ce != hipSuccess) {
        // fallback: ordinary launches (identical phase bodies)
        k_scatter_prep<<<NBg + gP, 256, 0, stream>>>(src, dst, E, bpos, ebuf,
                                                     W1, W2, W3, Wp1, bp1, Wp2, bp2,
                                                     Wt, Wft, bfh, NBg, CHA);
        k_degfill<<<NB, 256, 0, stream>>>(ebuf, bpos, cnt, nrm, offN, dh, csr, N);
        k_degscatter<<<gN, 256, 0, stream>>>(cnt, N, dh, binpos, offN, perm, pd2);
    }

    const int gG = (N + 63) / 64;
    const int gF = (N + 15) / 16;

    gemm_mfma_f32<<<gG, 256, 0, stream>>>(x, Wt, nrm, Ab, N);
    agg_gemm<<<gF, 256, 0, stream>>>((const uint4*)Ab, csr, pd2, perm, b1,
                                     Wt + DH * DH, Bb, N);
    agg_gemm<<<gF, 256, 0, stream>>>((const uint4*)Bb, csr, pd2, perm, b2,
                                     Wt + 2 * DH * DH, Ab, N);
    agg_head<<<gF, 256, 0, stream>>>((const uint4*)Ab, csr, pd2, perm, b3,
                                     Wft, bfh, out, N);
}

// Round 8
// 388.500 us; speedup vs baseline: 1.9223x; 1.9223x over previous
//
#include <hip/hip_runtime.h>
#include <hip/hip_bf16.h>
#include <math.h>

// ---------------------------------------------------------------------------
// GCN: 3x GCNConv(128->128) + fused (Wp1@Wp2) head + log_softmax.
// Round 19: revert R18's cooperative fusion (grid.sync cost ~100+us each ->
// prep_fused 390us alone; lesson: kernel-boundary drains are far cheaper
// than grid.sync at ~800-block scale on MI355X). Base = R17/R6 (378.5us).
// Changes vs R6:
//  - CH 4096 -> 2048: scatter blocks 391 -> 782, halves tail-dominated
//    makespan of the scatter phase.
//  - deg_scatter and gemm_mfma_f32 fused into one launch (disjoint block
//    ranges; both depend only on bucket_degfill). One less launch + drain;
//    391 degscatter blocks fill CUs alongside 1563 gemm blocks.
// agg/gather unchanged (at compulsory-traffic wall: FETCH ~191MB = per-XCD
// unique-row floor, fill pinned ~2.8 TB/s across R3-R6 variants).
// ---------------------------------------------------------------------------

#define DH 128     // feature dim (D == H == 128)
#define NC 40      // classes
#define BN 128     // nodes per bucket
#define MAXNB 1024 // max buckets (N <= 131072)
#define CAP 2560   // edge capacity per bucket (mean 2048, +11 sigma)
#define CH 2048    // edges per scatter block
#define SP 136     // LDS row stride (elems): 128 + 8 pad
#define NPREP (3 * DH * DH + 48 * DH + 48)

typedef __attribute__((ext_vector_type(8))) short bf16x8;
typedef __attribute__((ext_vector_type(4))) float f32x4;

__device__ __forceinline__ unsigned short f2bf(float f) {
    unsigned u = __float_as_uint(f);
    unsigned r = (u + 0x7fffu + ((u >> 16) & 1u)) >> 16;   // RNE
    return (unsigned short)r;
}
__device__ __forceinline__ unsigned pack2(float lo, float hi) {
    return (unsigned)f2bf(lo) | ((unsigned)f2bf(hi) << 16);
}

// ---------------- E-pass 1 + weight prep (fused grid) -----------------------

__global__ __launch_bounds__(256) void bucket_scatter_prep(
        const int* __restrict__ src, const int* __restrict__ dst, int E,
        unsigned* __restrict__ bpos, unsigned* __restrict__ ebuf,
        const float* __restrict__ W1, const float* __restrict__ W2,
        const float* __restrict__ W3, const float* __restrict__ Wp1,
        const float* __restrict__ bp1, const float* __restrict__ Wp2,
        const float* __restrict__ bp2, unsigned short* __restrict__ Wt,
        unsigned short* __restrict__ Wft, float* __restrict__ bfh, int gC) {
    __shared__ unsigned hist[MAXNB];
    __shared__ unsigned gbase[MAXNB];
    __shared__ unsigned lim[MAXNB];
    __shared__ unsigned cur[MAXNB];
    const int tid = threadIdx.x;

    if (blockIdx.x >= gC) {               // ---- weight-prep tail blocks ----
        int id = (blockIdx.x - gC) * 256 + tid;
        if (id < 3 * DH * DH) {
            int l = id >> 14, r = id & (DH * DH - 1);
            int k = r >> 7, n = r & 127;
            const float* W = (l == 0) ? W1 : (l == 1) ? W2 : W3;
            Wt[l * DH * DH + n * DH + k] = f2bf(W[k * DH + n]);
        } else if (id < 3 * DH * DH + 48 * DH) {
            int o = id - 3 * DH * DH;
            int c = o >> 7, k = o & 127;
            float acc = 0.f;
            if (c < NC)
                for (int j = 0; j < DH; ++j) acc += Wp1[k * DH + j] * Wp2[j * NC + c];
            Wft[c * DH + k] = f2bf(acc);
        } else if (id < NPREP) {
            int c = id - 3 * DH * DH - 48 * DH;
            float acc = 0.f;
            if (c < NC) {
                acc = bp2[c];
                for (int j = 0; j < DH; ++j) acc += bp1[j] * Wp2[j * NC + c];
            }
            bfh[c] = acc;
        }
        return;
    }

    const int e0 = blockIdx.x * CH;
    const int nE = min(CH, E - e0);
    const int nE4 = nE & ~3;

    for (int i = tid; i < MAXNB; i += 256) { hist[i] = 0; cur[i] = 0; }
    __syncthreads();
    for (int i = tid * 4; i < nE4; i += 1024) {
        int4 dv = *(const int4*)(dst + e0 + i);
        atomicAdd(&hist[(unsigned)dv.x >> 7], 1u);
        atomicAdd(&hist[(unsigned)dv.y >> 7], 1u);
        atomicAdd(&hist[(unsigned)dv.z >> 7], 1u);
        atomicAdd(&hist[(unsigned)dv.w >> 7], 1u);
    }
    for (int i = nE4 + tid; i < nE; i += 256)
        atomicAdd(&hist[(unsigned)dst[e0 + i] >> 7], 1u);
    __syncthreads();
    for (int i = tid; i < MAXNB; i += 256) {
        unsigned h = hist[i];
        if (h) {
            unsigned o = (unsigned)i * CAP + atomicAdd(&bpos[i], h);
            gbase[i] = o;
            lim[i] = min(o + h, (unsigned)(i + 1) * CAP);
        }
    }
    __syncthreads();
    for (int i = tid * 4; i < nE4; i += 1024) {
        int4 sv = *(const int4*)(src + e0 + i);
        int4 dv = *(const int4*)(dst + e0 + i);
        {
            unsigned b = (unsigned)dv.x >> 7;
            unsigned p = gbase[b] + atomicAdd(&cur[b], 1u);
            if (p < lim[b]) ebuf[p] = ((unsigned)sv.x << 7) | ((unsigned)dv.x & 127u);
        }
        {
            unsigned b = (unsigned)dv.y >> 7;
            unsigned p = gbase[b] + atomicAdd(&cur[b], 1u);
            if (p < lim[b]) ebuf[p] = ((unsigned)sv.y << 7) | ((unsigned)dv.y & 127u);
        }
        {
            unsigned b = (unsigned)dv.z >> 7;
            unsigned p = gbase[b] + atomicAdd(&cur[b], 1u);
            if (p < lim[b]) ebuf[p] = ((unsigned)sv.z << 7) | ((unsigned)dv.z & 127u);
        }
        {
            unsigned b = (unsigned)dv.w >> 7;
            unsigned p = gbase[b] + atomicAdd(&cur[b], 1u);
            if (p < lim[b]) ebuf[p] = ((unsigned)sv.w << 7) | ((unsigned)dv.w & 127u);
        }
    }
    for (int i = nE4 + tid; i < nE; i += 256) {
        int s = src[e0 + i];
        int d = dst[e0 + i];
        unsigned b = (unsigned)d >> 7;
        unsigned p = gbase[b] + atomicAdd(&cur[b], 1u);
        if (p < lim[b]) ebuf[p] = ((unsigned)s << 7) | ((unsigned)d & 127u);
    }
}

// ---------------- E-pass 2: degree + nrm + dh + grouped CSR (merged) --------

__global__ __launch_bounds__(256) void bucket_degfill(const unsigned* __restrict__ ebuf,
                                                      const unsigned* __restrict__ bpos,
                                                      unsigned* __restrict__ cnt,
                                                      float* __restrict__ nrm,
                                                      unsigned* __restrict__ offN,
                                                      unsigned* __restrict__ dh,
                                                      int* __restrict__ csr, int N) {
    __shared__ unsigned h[BN], lb[BN], cur[BN];
    __shared__ int lcsr[CAP];
    __shared__ unsigned dhh[256];
    __shared__ unsigned tot;

    int b = blockIdx.x, tid = threadIdx.x;
    unsigned ebase = (unsigned)b * CAP;
    unsigned used = min(bpos[b], (unsigned)CAP);
    unsigned used4 = used & ~3u;

    if (tid < BN) { h[tid] = 0; cur[tid] = 0; }
    dhh[tid] = 0;
    if (tid == 0) tot = 0;
    __syncthreads();

    for (unsigned i = tid * 4; i < used4; i += 1024) {
        uint4 v = *(const uint4*)(ebuf + ebase + i);
        atomicAdd(&h[v.x & 127u], 1u);
        atomicAdd(&h[v.y & 127u], 1u);
        atomicAdd(&h[v.z & 127u], 1u);
        atomicAdd(&h[v.w & 127u], 1u);
    }
    for (unsigned i = used4 + tid; i < used; i += 256)
        atomicAdd(&h[ebuf[ebase + i] & 127u], 1u);
    __syncthreads();

    if (tid < BN) {
        unsigned m = h[tid];
        lb[tid] = m ? atomicAdd(&tot, m) : 0u;
    }
    __syncthreads();

    for (unsigned i = tid * 4; i < used4; i += 1024) {
        uint4 v = *(const uint4*)(ebuf + ebase + i);
        {
            unsigned nl = v.x & 127u;
            unsigned r = atomicAdd(&cur[nl], 1u);
            lcsr[lb[nl] + r] = (int)(v.x >> 7);
        }
        {
            unsigned nl = v.y & 127u;
            unsigned r = atomicAdd(&cur[nl], 1u);
            lcsr[lb[nl] + r] = (int)(v.y >> 7);
        }
        {
            unsigned nl = v.z & 127u;
            unsigned r = atomicAdd(&cur[nl], 1u);
            lcsr[lb[nl] + r] = (int)(v.z >> 7);
        }
        {
            unsigned nl = v.w & 127u;
            unsigned r = atomicAdd(&cur[nl], 1u);
            lcsr[lb[nl] + r] = (int)(v.w >> 7);
        }
    }
    for (unsigned i = used4 + tid; i < used; i += 256) {
        unsigned v = ebuf[ebase + i];
        unsigned nl = v & 127u;
        unsigned r = atomicAdd(&cur[nl], 1u);
        lcsr[lb[nl] + r] = (int)(v >> 7);
    }

    if (tid < BN) {
        int node = b * BN + tid;
        if (node < N) {
            unsigned m = h[tid];
            cnt[node] = m;
            nrm[node] = rsqrtf((float)m + 1.0f);
            offN[node] = ebase + lb[tid];
            atomicAdd(&dhh[min(m, 255u)], 1u);
        }
    }
    __syncthreads();

    for (unsigned i = tid * 4; i < used4; i += 1024)
        *(int4*)(csr + ebase + i) = *(const int4*)&lcsr[i];
    for (unsigned i = used4 + tid; i < used; i += 256)
        csr[ebase + i] = lcsr[i];
    if (dhh[tid]) atomicAdd(&dh[tid], dhh[tid]);
}

// ---------------- fused: deg_scatter (perm build) || layer-1 MFMA GEMM ------
// Both depend only on bucket_degfill. Blocks [0,gN): perm build.
// Blocks [gN, gN+gG): Ab = bf16(nrm * (x_f32 @ W1)), 16x128/wave.

__global__ __launch_bounds__(256) void degscat_gemm(
        const unsigned* __restrict__ cnt, int N,
        const unsigned* __restrict__ dh, unsigned* __restrict__ binpos,
        const unsigned* __restrict__ offN, int* __restrict__ perm,
        unsigned* __restrict__ pd2,
        const float* __restrict__ X, const unsigned short* __restrict__ Wt,
        const float* __restrict__ nrm, unsigned short* __restrict__ outb,
        int gN) {
    __shared__ unsigned hh[256], base[256], cur[256], sdh[256], sns[256];
    const int tid = threadIdx.x;

    if (blockIdx.x < (unsigned)gN) {      // ---- perm build ----
        int t = tid;
        hh[t] = 0; cur[t] = 0; sdh[t] = dh[t];
        __syncthreads();
        unsigned ns = 0;
        for (int d = t + 1; d < 256; ++d) ns += sdh[d];
        sns[t] = ns;
        int i = blockIdx.x * 256 + t;
        unsigned d = 0;
        if (i < N) { d = min(cnt[i], 255u); atomicAdd(&hh[d], 1u); }
        __syncthreads();
        if (hh[t]) base[t] = sns[t] + atomicAdd(&binpos[t], hh[t]);
        __syncthreads();
        if (i < N) {
            unsigned r = atomicAdd(&cur[d], 1u);
            unsigned idx = base[d] + r;
            perm[idx] = i;
            pd2[idx] = (offN[i] << 9) | min(cnt[i], 511u);
        }
        return;
    }

    // ---- GEMM ----
    const int wave = tid >> 6;
    const int lane = tid & 63;
    const int m = lane & 15;
    const int quad = lane >> 4;
    const int rbase = (blockIdx.x - gN) * 64 + wave * 16;

    union U8 { bf16x8 v; unsigned u[4]; };

    f32x4 acc[8];
#pragma unroll
    for (int ct = 0; ct < 8; ++ct) acc[ct] = (f32x4){0.f, 0.f, 0.f, 0.f};

#pragma unroll
    for (int kt = 0; kt < 4; ++kt) {
        const int kof = kt * 32 + quad * 8;
        int r = rbase + m;
        r = (r < N) ? r : (N - 1);
        const float* p = X + (size_t)r * DH + kof;
        float4 u0 = *(const float4*)p;
        float4 u1 = *(const float4*)(p + 4);
        U8 t;
        t.u[0] = pack2(u0.x, u0.y);
        t.u[1] = pack2(u0.z, u0.w);
        t.u[2] = pack2(u1.x, u1.y);
        t.u[3] = pack2(u1.z, u1.w);
        bf16x8 a = t.v;
        bf16x8 b[8];
#pragma unroll
        for (int ct = 0; ct < 8; ++ct)
            b[ct] = *(const bf16x8*)(Wt + (ct * 16 + m) * DH + kof);
#pragma unroll
        for (int ct = 0; ct < 8; ++ct)
            acc[ct] = __builtin_amdgcn_mfma_f32_16x16x32_bf16(a, b[ct], acc[ct], 0, 0, 0);
    }

#pragma unroll
    for (int reg = 0; reg < 4; ++reg) {
        int r = rbase + quad * 4 + reg;
        if (r < N) {
            float s = nrm[r];
#pragma unroll
            for (int ct = 0; ct < 8; ++ct)
                outb[(size_t)r * DH + ct * 16 + m] = f2bf(acc[ct][reg] * s);
        }
    }
}

// ---------------- gather phase (perm order) ---------------------------------

__device__ __forceinline__ void bf8_add(float* acc, uint4 v) {
    acc[0] += __uint_as_float(v.x << 16);
    acc[1] += __uint_as_float(v.x & 0xffff0000u);
    acc[2] += __uint_as_float(v.y << 16);
    acc[3] += __uint_as_float(v.y & 0xffff0000u);
    acc[4] += __uint_as_float(v.z << 16);
    acc[5] += __uint_as_float(v.z & 0xffff0000u);
    acc[6] += __uint_as_float(v.w << 16);
    acc[7] += __uint_as_float(v.w & 0xffff0000u);
}

__device__ __forceinline__ void gather_phase(const uint4* __restrict__ Abf,
                                             const int* __restrict__ csr,
                                             const unsigned* __restrict__ pd2,
                                             const int* __restrict__ perm,
                                             const float* __restrict__ bias,
                                             unsigned short (*sA)[SP],
                                             int* snode, float* snrm, int N) {
    const int tid = threadIdx.x;
    const int g = tid >> 4;
    const int lane = tid & 15;
    const int idx = blockIdx.x * 16 + g;
    if (idx < N) {
        const unsigned pd = pd2[idx];
        const unsigned o = pd >> 9;
        const unsigned d = pd & 511u;
        const int node = perm[idx];

        // up-front csr prefetch: lane-distributed, covers e < 64
        int i0 = 0, i1 = 0, i2 = 0, i3 = 0;
        if ((unsigned)lane < d)        i0 = csr[o + lane];
        if ((unsigned)(16 + lane) < d) i1 = csr[o + 16 + lane];
        if ((unsigned)(32 + lane) < d) i2 = csr[o + 32 + lane];
        if ((unsigned)(48 + lane) < d) i3 = csr[o + 48 + lane];

        float acc[8];
        {
            uint4 v = Abf[(size_t)node * 16 + lane];   // self term
            acc[0] = __uint_as_float(v.x << 16);
            acc[1] = __uint_as_float(v.x & 0xffff0000u);
            acc[2] = __uint_as_float(v.y << 16);
            acc[3] = __uint_as_float(v.y & 0xffff0000u);
            acc[4] = __uint_as_float(v.z << 16);
            acc[5] = __uint_as_float(v.z & 0xffff0000u);
            acc[6] = __uint_as_float(v.w << 16);
            acc[7] = __uint_as_float(v.w & 0xffff0000u);
        }

        const unsigned dl = min(d, 64u);
        const int sb = g << 4;
        unsigned e = 0;
        for (; e + 4 <= dl; e += 4) {
            int rsel = (e < 16) ? i0 : (e < 32) ? i1 : (e < 48) ? i2 : i3;
            int bb = sb + (int)(e & 15u);
            int s0 = __shfl(rsel, bb + 0);
            int s1 = __shfl(rsel, bb + 1);
            int s2 = __shfl(rsel, bb + 2);
            int s3 = __shfl(rsel, bb + 3);
            uint4 v0 = Abf[(size_t)s0 * 16 + lane];
            uint4 v1 = Abf[(size_t)s1 * 16 + lane];
            uint4 v2 = Abf[(size_t)s2 * 16 + lane];
            uint4 v3 = Abf[(size_t)s3 * 16 + lane];
            bf8_add(acc, v0);
            bf8_add(acc, v1);
            bf8_add(acc, v2);
            bf8_add(acc, v3);
        }
        for (; e < dl; ++e) {
            int rsel = (e < 16) ? i0 : (e < 32) ? i1 : (e < 48) ? i2 : i3;
            int s = __shfl(rsel, sb + (int)(e & 15u));
            uint4 v = Abf[(size_t)s * 16 + lane];
            bf8_add(acc, v);
        }
        for (; e < d; ++e) {                     // d > 64 spill (P ~ 0)
            int s = csr[o + e];
            uint4 v = Abf[(size_t)s * 16 + lane];
            bf8_add(acc, v);
        }

        float nm = rsqrtf((float)d + 1.0f);
        if (lane == 0) { snode[g] = node; snrm[g] = nm; }
        float4 b0 = *(const float4*)(bias + lane * 8);
        float4 b1 = *(const float4*)(bias + lane * 8 + 4);
        uint4 ov;
        ov.x = pack2(fmaxf(acc[0] * nm + b0.x, 0.f), fmaxf(acc[1] * nm + b0.y, 0.f));
        ov.y = pack2(fmaxf(acc[2] * nm + b0.z, 0.f), fmaxf(acc[3] * nm + b0.w, 0.f));
        ov.z = pack2(fmaxf(acc[4] * nm + b1.x, 0.f), fmaxf(acc[5] * nm + b1.y, 0.f));
        ov.w = pack2(fmaxf(acc[6] * nm + b1.z, 0.f), fmaxf(acc[7] * nm + b1.w, 0.f));
        *(uint4*)&sA[g][lane * 8] = ov;
    }
    __syncthreads();
}

// ---------------- fused: aggregate + next-layer GEMM ------------------------

__global__ __launch_bounds__(256) void agg_gemm(const uint4* __restrict__ Abf,
                                                const int* __restrict__ csr,
                                                const unsigned* __restrict__ pd2,
                                                const int* __restrict__ perm,
                                                const float* __restrict__ bias,
                                                const unsigned short* __restrict__ Wt,
                                                unsigned short* __restrict__ outb, int N) {
    __shared__ unsigned short sA[16][SP];
    __shared__ int snode[16];
    __shared__ float snrm[16];
    gather_phase(Abf, csr, pd2, perm, bias, sA, snode, snrm, N);

    const int tid = threadIdx.x;
    const int wave = tid >> 6;
    const int l64 = tid & 63;
    const int m = l64 & 15;
    const int quad = l64 >> 4;

    f32x4 acc[2];
    acc[0] = (f32x4){0.f, 0.f, 0.f, 0.f};
    acc[1] = (f32x4){0.f, 0.f, 0.f, 0.f};

#pragma unroll
    for (int kt = 0; kt < 4; ++kt) {
        const int kof = kt * 32 + quad * 8;
        bf16x8 a = *(const bf16x8*)&sA[m][kof];
#pragma unroll
        for (int c2 = 0; c2 < 2; ++c2) {
            const int ct = wave * 2 + c2;
            bf16x8 b = *(const bf16x8*)(Wt + (ct * 16 + m) * DH + kof);
            acc[c2] = __builtin_amdgcn_mfma_f32_16x16x32_bf16(a, b, acc[c2], 0, 0, 0);
        }
    }

#pragma unroll
    for (int reg = 0; reg < 4; ++reg) {
        int idx = blockIdx.x * 16 + quad * 4 + reg;
        if (idx < N) {
            int r = snode[quad * 4 + reg];
            float s = snrm[quad * 4 + reg];
#pragma unroll
            for (int c2 = 0; c2 < 2; ++c2)
                outb[(size_t)r * DH + (wave * 2 + c2) * 16 + m] = f2bf(acc[c2][reg] * s);
        }
    }
}

// ---------------- fused: aggregate + head GEMM + log_softmax ----------------

__global__ __launch_bounds__(256) void agg_head(const uint4* __restrict__ Abf,
                                                const int* __restrict__ csr,
                                                const unsigned* __restrict__ pd2,
                                                const int* __restrict__ perm,
                                                const float* __restrict__ bias,
                                                const unsigned short* __restrict__ Wft,
                                                const float* __restrict__ bfh,
                                                float* __restrict__ out, int N) {
    __shared__ unsigned short sA[16][SP];
    __shared__ int snode[16];
    __shared__ float snrm[16];
    gather_phase(Abf, csr, pd2, perm, bias, sA, snode, snrm, N);

    const int tid = threadIdx.x;
    if (tid >= 64) return;                 // one wave does the 16x48 head
    const int m = tid & 15;
    const int quad = tid >> 4;

    f32x4 acc[3];
#pragma unroll
    for (int ct = 0; ct < 3; ++ct) acc[ct] = (f32x4){0.f, 0.f, 0.f, 0.f};

#pragma unroll
    for (int kt = 0; kt < 4; ++kt) {
        const int kof = kt * 32 + quad * 8;
        bf16x8 a = *(const bf16x8*)&sA[m][kof];
#pragma unroll
        for (int ct = 0; ct < 3; ++ct) {
            bf16x8 b = *(const bf16x8*)(Wft + (ct * 16 + m) * DH + kof);
            acc[ct] = __builtin_amdgcn_mfma_f32_16x16x32_bf16(a, b, acc[ct], 0, 0, 0);
        }
    }

    float bias0 = bfh[m];
    float bias1 = bfh[16 + m];
    float bias2 = bfh[32 + m];

#pragma unroll
    for (int reg = 0; reg < 4; ++reg) {
        float v0 = acc[0][reg] + bias0;
        float v1 = acc[1][reg] + bias1;
        float v2 = (m < 8) ? (acc[2][reg] + bias2) : -1e30f;
        float mx = fmaxf(fmaxf(v0, v1), v2);
#pragma unroll
        for (int dlt = 1; dlt < 16; dlt <<= 1) mx = fmaxf(mx, __shfl_xor(mx, dlt));
        float s = __expf(v0 - mx) + __expf(v1 - mx) + ((m < 8) ? __expf(v2 - mx) : 0.f);
#pragma unroll
        for (int dlt = 1; dlt < 16; dlt <<= 1) s += __shfl_xor(s, dlt);
        float ls = mx + __logf(s);
        int idx = blockIdx.x * 16 + quad * 4 + reg;
        if (idx < N) {
            int r = snode[quad * 4 + reg];
            out[(size_t)r * NC + m] = v0 - ls;
            out[(size_t)r * NC + 16 + m] = v1 - ls;
            if (m < 8) out[(size_t)r * NC + 32 + m] = v2 - ls;
        }
    }
}

// ---------------------------------------------------------------------------

extern "C" void kernel_launch(void* const* d_in, const int* in_sizes, int n_in,
                              void* d_out, int out_size, void* d_ws, size_t ws_size,
                              hipStream_t stream) {
    const float* x   = (const float*)d_in[0];
    const int*   ei  = (const int*)d_in[1];
    const float* W1  = (const float*)d_in[2];
    const float* b1  = (const float*)d_in[3];
    const float* W2  = (const float*)d_in[4];
    const float* b2  = (const float*)d_in[5];
    const float* W3  = (const float*)d_in[6];
    const float* b3  = (const float*)d_in[7];
    const float* Wp1 = (const float*)d_in[8];
    const float* bp1 = (const float*)d_in[9];
    const float* Wp2 = (const float*)d_in[10];
    const float* bp2 = (const float*)d_in[11];
    float* out = (float*)d_out;

    const int N = in_sizes[0] / DH;
    const int E = in_sizes[1] / 2;
    const int* src = ei;
    const int* dst = ei + E;
    const int NB = (N + BN - 1) / BN;

    // workspace carve (all 16B aligned)
    char* w = (char*)d_ws;
    unsigned short* Ab  = (unsigned short*)w; w += (size_t)N * DH * 2;
    unsigned short* Bb  = (unsigned short*)w; w += (size_t)N * DH * 2;
    int*      csr    = (int*)w;      w += (size_t)NB * CAP * 4;
    unsigned* ebuf   = (unsigned*)w; w += (size_t)NB * CAP * 4;
    // ---- zeroed region (one memset): dh + binpos + bpos ----
    unsigned* dh     = (unsigned*)w; w += 256 * 4;
    unsigned* binpos = (unsigned*)w; w += 256 * 4;
    unsigned* bpos   = (unsigned*)w; w += MAXNB * 4;
    // ---- end zeroed region ----
    unsigned* cnt    = (unsigned*)w; w += (size_t)N * 4;
    float*    nrm    = (float*)w;    w += (size_t)N * 4;
    unsigned* offN   = (unsigned*)w; w += (size_t)N * 4;
    unsigned* pd2    = (unsigned*)w; w += (size_t)((N + 31) & ~31) * 4;
    int*      perm   = (int*)w;      w += (size_t)((N + 31) & ~31) * 4;
    unsigned short* Wt  = (unsigned short*)w; w += 3 * DH * DH * 2;
    unsigned short* Wft = (unsigned short*)w; w += 48 * DH * 2;
    float*    bfh    = (float*)w;    w += 64 * 4;

    const int gC = (E + CH - 1) / CH;
    const int gN = (N + 255) / 256;
    const int gP = (NPREP + 255) / 256;
    const int gG = (N + 63) / 64;
    const int gF = (N + 15) / 16;

    hipMemsetAsync(dh, 0, 256 * 4 + 256 * 4 + MAXNB * 4, stream);
    bucket_scatter_prep<<<gC + gP, 256, 0, stream>>>(src, dst, E, bpos, ebuf,
                                                     W1, W2, W3, Wp1, bp1, Wp2, bp2,
                                                     Wt, Wft, bfh, gC);
    bucket_degfill<<<NB, 256, 0, stream>>>(ebuf, bpos, cnt, nrm, offN, dh, csr, N);
    degscat_gemm<<<gN + gG, 256, 0, stream>>>(cnt, N, dh, binpos, offN, perm, pd2,
                                              x, Wt, nrm, Ab, gN);

    agg_gemm<<<gF, 256, 0, stream>>>((const uint4*)Ab, csr, pd2, perm, b1,
                                     Wt + DH * DH, Bb, N);
    agg_gemm<<<gF, 256, 0, stream>>>((const uint4*)Bb, csr, pd2, perm, b2,
                                     Wt + 2 * DH * DH, Ab, N);
    agg_head<<<gF, 256, 0, stream>>>((const uint4*)Ab, csr, pd2, perm, b3,
                                     Wft, bfh, out, N);
}

// Round 9
// 369.991 us; speedup vs baseline: 2.0185x; 1.0500x over previous
//
#include <hip/hip_runtime.h>
#include <hip/hip_bf16.h>
#include <math.h>

// ---------------------------------------------------------------------------
// GCN: 3x GCNConv(128->128) + fused (Wp1@Wp2) head + log_softmax.
// Round 20: recombine verified-good pieces only.
//  - CH back to 4096 (R8's 2048 halved per-block edges but kept fixed
//    per-block costs: 2x1024-word LDS init + ~800 cursor atomics/block ->
//    +10us). 391 scatter blocks + 217 weight-prep tail blocks.
//  - Keep degscat_gemm fusion (one less launch+drain than R6) but GEMM
//    blocks FIRST ([0,gG)), perm-build blocks tail ([gG,gG+gN)) so the
//    long-pole GEMM starts dispatching immediately.
// agg/gather unchanged: at compulsory-traffic wall (FETCH ~191MB = per-XCD
// unique-row floor; L2-miss fill pinned ~2.8 TB/s across R3-R8 variants;
// deeper ILP hurt twice via occupancy).
// ---------------------------------------------------------------------------

#define DH 128     // feature dim (D == H == 128)
#define NC 40      // classes
#define BN 128     // nodes per bucket
#define MAXNB 1024 // max buckets (N <= 131072)
#define CAP 2560   // edge capacity per bucket (mean 2048, +11 sigma)
#define CH 4096    // edges per scatter block
#define SP 136     // LDS row stride (elems): 128 + 8 pad
#define NPREP (3 * DH * DH + 48 * DH + 48)

typedef __attribute__((ext_vector_type(8))) short bf16x8;
typedef __attribute__((ext_vector_type(4))) float f32x4;

__device__ __forceinline__ unsigned short f2bf(float f) {
    unsigned u = __float_as_uint(f);
    unsigned r = (u + 0x7fffu + ((u >> 16) & 1u)) >> 16;   // RNE
    return (unsigned short)r;
}
__device__ __forceinline__ unsigned pack2(float lo, float hi) {
    return (unsigned)f2bf(lo) | ((unsigned)f2bf(hi) << 16);
}

// ---------------- E-pass 1 + weight prep (fused grid) -----------------------

__global__ __launch_bounds__(256) void bucket_scatter_prep(
        const int* __restrict__ src, const int* __restrict__ dst, int E,
        unsigned* __restrict__ bpos, unsigned* __restrict__ ebuf,
        const float* __restrict__ W1, const float* __restrict__ W2,
        const float* __restrict__ W3, const float* __restrict__ Wp1,
        const float* __restrict__ bp1, const float* __restrict__ Wp2,
        const float* __restrict__ bp2, unsigned short* __restrict__ Wt,
        unsigned short* __restrict__ Wft, float* __restrict__ bfh, int gC) {
    __shared__ unsigned hist[MAXNB];
    __shared__ unsigned gbase[MAXNB];
    __shared__ unsigned lim[MAXNB];
    __shared__ unsigned cur[MAXNB];
    const int tid = threadIdx.x;

    if (blockIdx.x >= gC) {               // ---- weight-prep tail blocks ----
        int id = (blockIdx.x - gC) * 256 + tid;
        if (id < 3 * DH * DH) {
            int l = id >> 14, r = id & (DH * DH - 1);
            int k = r >> 7, n = r & 127;
            const float* W = (l == 0) ? W1 : (l == 1) ? W2 : W3;
            Wt[l * DH * DH + n * DH + k] = f2bf(W[k * DH + n]);
        } else if (id < 3 * DH * DH + 48 * DH) {
            int o = id - 3 * DH * DH;
            int c = o >> 7, k = o & 127;
            float acc = 0.f;
            if (c < NC)
                for (int j = 0; j < DH; ++j) acc += Wp1[k * DH + j] * Wp2[j * NC + c];
            Wft[c * DH + k] = f2bf(acc);
        } else if (id < NPREP) {
            int c = id - 3 * DH * DH - 48 * DH;
            float acc = 0.f;
            if (c < NC) {
                acc = bp2[c];
                for (int j = 0; j < DH; ++j) acc += bp1[j] * Wp2[j * NC + c];
            }
            bfh[c] = acc;
        }
        return;
    }

    const int e0 = blockIdx.x * CH;
    const int nE = min(CH, E - e0);
    const int nE4 = nE & ~3;

    for (int i = tid; i < MAXNB; i += 256) { hist[i] = 0; cur[i] = 0; }
    __syncthreads();
    for (int i = tid * 4; i < nE4; i += 1024) {
        int4 dv = *(const int4*)(dst + e0 + i);
        atomicAdd(&hist[(unsigned)dv.x >> 7], 1u);
        atomicAdd(&hist[(unsigned)dv.y >> 7], 1u);
        atomicAdd(&hist[(unsigned)dv.z >> 7], 1u);
        atomicAdd(&hist[(unsigned)dv.w >> 7], 1u);
    }
    for (int i = nE4 + tid; i < nE; i += 256)
        atomicAdd(&hist[(unsigned)dst[e0 + i] >> 7], 1u);
    __syncthreads();
    for (int i = tid; i < MAXNB; i += 256) {
        unsigned h = hist[i];
        if (h) {
            unsigned o = (unsigned)i * CAP + atomicAdd(&bpos[i], h);
            gbase[i] = o;
            lim[i] = min(o + h, (unsigned)(i + 1) * CAP);
        }
    }
    __syncthreads();
    for (int i = tid * 4; i < nE4; i += 1024) {
        int4 sv = *(const int4*)(src + e0 + i);
        int4 dv = *(const int4*)(dst + e0 + i);
        {
            unsigned b = (unsigned)dv.x >> 7;
            unsigned p = gbase[b] + atomicAdd(&cur[b], 1u);
            if (p < lim[b]) ebuf[p] = ((unsigned)sv.x << 7) | ((unsigned)dv.x & 127u);
        }
        {
            unsigned b = (unsigned)dv.y >> 7;
            unsigned p = gbase[b] + atomicAdd(&cur[b], 1u);
            if (p < lim[b]) ebuf[p] = ((unsigned)sv.y << 7) | ((unsigned)dv.y & 127u);
        }
        {
            unsigned b = (unsigned)dv.z >> 7;
            unsigned p = gbase[b] + atomicAdd(&cur[b], 1u);
            if (p < lim[b]) ebuf[p] = ((unsigned)sv.z << 7) | ((unsigned)dv.z & 127u);
        }
        {
            unsigned b = (unsigned)dv.w >> 7;
            unsigned p = gbase[b] + atomicAdd(&cur[b], 1u);
            if (p < lim[b]) ebuf[p] = ((unsigned)sv.w << 7) | ((unsigned)dv.w & 127u);
        }
    }
    for (int i = nE4 + tid; i < nE; i += 256) {
        int s = src[e0 + i];
        int d = dst[e0 + i];
        unsigned b = (unsigned)d >> 7;
        unsigned p = gbase[b] + atomicAdd(&cur[b], 1u);
        if (p < lim[b]) ebuf[p] = ((unsigned)s << 7) | ((unsigned)d & 127u);
    }
}

// ---------------- E-pass 2: degree + nrm + dh + grouped CSR (merged) --------

__global__ __launch_bounds__(256) void bucket_degfill(const unsigned* __restrict__ ebuf,
                                                      const unsigned* __restrict__ bpos,
                                                      unsigned* __restrict__ cnt,
                                                      float* __restrict__ nrm,
                                                      unsigned* __restrict__ offN,
                                                      unsigned* __restrict__ dh,
                                                      int* __restrict__ csr, int N) {
    __shared__ unsigned h[BN], lb[BN], cur[BN];
    __shared__ int lcsr[CAP];
    __shared__ unsigned dhh[256];
    __shared__ unsigned tot;

    int b = blockIdx.x, tid = threadIdx.x;
    unsigned ebase = (unsigned)b * CAP;
    unsigned used = min(bpos[b], (unsigned)CAP);
    unsigned used4 = used & ~3u;

    if (tid < BN) { h[tid] = 0; cur[tid] = 0; }
    dhh[tid] = 0;
    if (tid == 0) tot = 0;
    __syncthreads();

    for (unsigned i = tid * 4; i < used4; i += 1024) {
        uint4 v = *(const uint4*)(ebuf + ebase + i);
        atomicAdd(&h[v.x & 127u], 1u);
        atomicAdd(&h[v.y & 127u], 1u);
        atomicAdd(&h[v.z & 127u], 1u);
        atomicAdd(&h[v.w & 127u], 1u);
    }
    for (unsigned i = used4 + tid; i < used; i += 256)
        atomicAdd(&h[ebuf[ebase + i] & 127u], 1u);
    __syncthreads();

    if (tid < BN) {
        unsigned m = h[tid];
        lb[tid] = m ? atomicAdd(&tot, m) : 0u;
    }
    __syncthreads();

    for (unsigned i = tid * 4; i < used4; i += 1024) {
        uint4 v = *(const uint4*)(ebuf + ebase + i);
        {
            unsigned nl = v.x & 127u;
            unsigned r = atomicAdd(&cur[nl], 1u);
            lcsr[lb[nl] + r] = (int)(v.x >> 7);
        }
        {
            unsigned nl = v.y & 127u;
            unsigned r = atomicAdd(&cur[nl], 1u);
            lcsr[lb[nl] + r] = (int)(v.y >> 7);
        }
        {
            unsigned nl = v.z & 127u;
            unsigned r = atomicAdd(&cur[nl], 1u);
            lcsr[lb[nl] + r] = (int)(v.z >> 7);
        }
        {
            unsigned nl = v.w & 127u;
            unsigned r = atomicAdd(&cur[nl], 1u);
            lcsr[lb[nl] + r] = (int)(v.w >> 7);
        }
    }
    for (unsigned i = used4 + tid; i < used; i += 256) {
        unsigned v = ebuf[ebase + i];
        unsigned nl = v & 127u;
        unsigned r = atomicAdd(&cur[nl], 1u);
        lcsr[lb[nl] + r] = (int)(v >> 7);
    }

    if (tid < BN) {
        int node = b * BN + tid;
        if (node < N) {
            unsigned m = h[tid];
            cnt[node] = m;
            nrm[node] = rsqrtf((float)m + 1.0f);
            offN[node] = ebase + lb[tid];
            atomicAdd(&dhh[min(m, 255u)], 1u);
        }
    }
    __syncthreads();

    for (unsigned i = tid * 4; i < used4; i += 1024)
        *(int4*)(csr + ebase + i) = *(const int4*)&lcsr[i];
    for (unsigned i = used4 + tid; i < used; i += 256)
        csr[ebase + i] = lcsr[i];
    if (dhh[tid]) atomicAdd(&dh[tid], dhh[tid]);
}

// ---------------- fused: layer-1 MFMA GEMM || deg_scatter (perm build) ------
// Both depend only on bucket_degfill. Blocks [0,gG): GEMM (long pole, starts
// first). Blocks [gG, gG+gN): perm build (short, tails).

__global__ __launch_bounds__(256) void degscat_gemm(
        const unsigned* __restrict__ cnt, int N,
        const unsigned* __restrict__ dh, unsigned* __restrict__ binpos,
        const unsigned* __restrict__ offN, int* __restrict__ perm,
        unsigned* __restrict__ pd2,
        const float* __restrict__ X, const unsigned short* __restrict__ Wt,
        const float* __restrict__ nrm, unsigned short* __restrict__ outb,
        int gG) {
    __shared__ unsigned hh[256], base[256], cur[256], sdh[256], sns[256];
    const int tid = threadIdx.x;

    if (blockIdx.x >= (unsigned)gG) {     // ---- perm build (tail blocks) ----
        int t = tid;
        hh[t] = 0; cur[t] = 0; sdh[t] = dh[t];
        __syncthreads();
        unsigned ns = 0;
        for (int d = t + 1; d < 256; ++d) ns += sdh[d];
        sns[t] = ns;
        int i = (blockIdx.x - gG) * 256 + t;
        unsigned d = 0;
        if (i < N) { d = min(cnt[i], 255u); atomicAdd(&hh[d], 1u); }
        __syncthreads();
        if (hh[t]) base[t] = sns[t] + atomicAdd(&binpos[t], hh[t]);
        __syncthreads();
        if (i < N) {
            unsigned r = atomicAdd(&cur[d], 1u);
            unsigned idx = base[d] + r;
            perm[idx] = i;
            pd2[idx] = (offN[i] << 9) | min(cnt[i], 511u);
        }
        return;
    }

    // ---- GEMM ----
    const int wave = tid >> 6;
    const int lane = tid & 63;
    const int m = lane & 15;
    const int quad = lane >> 4;
    const int rbase = blockIdx.x * 64 + wave * 16;

    union U8 { bf16x8 v; unsigned u[4]; };

    f32x4 acc[8];
#pragma unroll
    for (int ct = 0; ct < 8; ++ct) acc[ct] = (f32x4){0.f, 0.f, 0.f, 0.f};

#pragma unroll
    for (int kt = 0; kt < 4; ++kt) {
        const int kof = kt * 32 + quad * 8;
        int r = rbase + m;
        r = (r < N) ? r : (N - 1);
        const float* p = X + (size_t)r * DH + kof;
        float4 u0 = *(const float4*)p;
        float4 u1 = *(const float4*)(p + 4);
        U8 t;
        t.u[0] = pack2(u0.x, u0.y);
        t.u[1] = pack2(u0.z, u0.w);
        t.u[2] = pack2(u1.x, u1.y);
        t.u[3] = pack2(u1.z, u1.w);
        bf16x8 a = t.v;
        bf16x8 b[8];
#pragma unroll
        for (int ct = 0; ct < 8; ++ct)
            b[ct] = *(const bf16x8*)(Wt + (ct * 16 + m) * DH + kof);
#pragma unroll
        for (int ct = 0; ct < 8; ++ct)
            acc[ct] = __builtin_amdgcn_mfma_f32_16x16x32_bf16(a, b[ct], acc[ct], 0, 0, 0);
    }

#pragma unroll
    for (int reg = 0; reg < 4; ++reg) {
        int r = rbase + quad * 4 + reg;
        if (r < N) {
            float s = nrm[r];
#pragma unroll
            for (int ct = 0; ct < 8; ++ct)
                outb[(size_t)r * DH + ct * 16 + m] = f2bf(acc[ct][reg] * s);
        }
    }
}

// ---------------- gather phase (perm order) ---------------------------------

__device__ __forceinline__ void bf8_add(float* acc, uint4 v) {
    acc[0] += __uint_as_float(v.x << 16);
    acc[1] += __uint_as_float(v.x & 0xffff0000u);
    acc[2] += __uint_as_float(v.y << 16);
    acc[3] += __uint_as_float(v.y & 0xffff0000u);
    acc[4] += __uint_as_float(v.z << 16);
    acc[5] += __uint_as_float(v.z & 0xffff0000u);
    acc[6] += __uint_as_float(v.w << 16);
    acc[7] += __uint_as_float(v.w & 0xffff0000u);
}

__device__ __forceinline__ void gather_phase(const uint4* __restrict__ Abf,
                                             const int* __restrict__ csr,
                                             const unsigned* __restrict__ pd2,
                                             const int* __restrict__ perm,
                                             const float* __restrict__ bias,
                                             unsigned short (*sA)[SP],
                                             int* snode, float* snrm, int N) {
    const int tid = threadIdx.x;
    const int g = tid >> 4;
    const int lane = tid & 15;
    const int idx = blockIdx.x * 16 + g;
    if (idx < N) {
        const unsigned pd = pd2[idx];
        const unsigned o = pd >> 9;
        const unsigned d = pd & 511u;
        const int node = perm[idx];

        // up-front csr prefetch: lane-distributed, covers e < 64
        int i0 = 0, i1 = 0, i2 = 0, i3 = 0;
        if ((unsigned)lane < d)        i0 = csr[o + lane];
        if ((unsigned)(16 + lane) < d) i1 = csr[o + 16 + lane];
        if ((unsigned)(32 + lane) < d) i2 = csr[o + 32 + lane];
        if ((unsigned)(48 + lane) < d) i3 = csr[o + 48 + lane];

        float acc[8];
        {
            uint4 v = Abf[(size_t)node * 16 + lane];   // self term
            acc[0] = __uint_as_float(v.x << 16);
            acc[1] = __uint_as_float(v.x & 0xffff0000u);
            acc[2] = __uint_as_float(v.y << 16);
            acc[3] = __uint_as_float(v.y & 0xffff0000u);
            acc[4] = __uint_as_float(v.z << 16);
            acc[5] = __uint_as_float(v.z & 0xffff0000u);
            acc[6] = __uint_as_float(v.w << 16);
            acc[7] = __uint_as_float(v.w & 0xffff0000u);
        }

        const unsigned dl = min(d, 64u);
        const int sb = g << 4;
        unsigned e = 0;
        for (; e + 4 <= dl; e += 4) {
            int rsel = (e < 16) ? i0 : (e < 32) ? i1 : (e < 48) ? i2 : i3;
            int bb = sb + (int)(e & 15u);
            int s0 = __shfl(rsel, bb + 0);
            int s1 = __shfl(rsel, bb + 1);
            int s2 = __shfl(rsel, bb + 2);
            int s3 = __shfl(rsel, bb + 3);
            uint4 v0 = Abf[(size_t)s0 * 16 + lane];
            uint4 v1 = Abf[(size_t)s1 * 16 + lane];
            uint4 v2 = Abf[(size_t)s2 * 16 + lane];
            uint4 v3 = Abf[(size_t)s3 * 16 + lane];
            bf8_add(acc, v0);
            bf8_add(acc, v1);
            bf8_add(acc, v2);
            bf8_add(acc, v3);
        }
        for (; e < dl; ++e) {
            int rsel = (e < 16) ? i0 : (e < 32) ? i1 : (e < 48) ? i2 : i3;
            int s = __shfl(rsel, sb + (int)(e & 15u));
            uint4 v = Abf[(size_t)s * 16 + lane];
            bf8_add(acc, v);
        }
        for (; e < d; ++e) {                     // d > 64 spill (P ~ 0)
            int s = csr[o + e];
            uint4 v = Abf[(size_t)s * 16 + lane];
            bf8_add(acc, v);
        }

        float nm = rsqrtf((float)d + 1.0f);
        if (lane == 0) { snode[g] = node; snrm[g] = nm; }
        float4 b0 = *(const float4*)(bias + lane * 8);
        float4 b1 = *(const float4*)(bias + lane * 8 + 4);
        uint4 ov;
        ov.x = pack2(fmaxf(acc[0] * nm + b0.x, 0.f), fmaxf(acc[1] * nm + b0.y, 0.f));
        ov.y = pack2(fmaxf(acc[2] * nm + b0.z, 0.f), fmaxf(acc[3] * nm + b0.w, 0.f));
        ov.z = pack2(fmaxf(acc[4] * nm + b1.x, 0.f), fmaxf(acc[5] * nm + b1.y, 0.f));
        ov.w = pack2(fmaxf(acc[6] * nm + b1.z, 0.f), fmaxf(acc[7] * nm + b1.w, 0.f));
        *(uint4*)&sA[g][lane * 8] = ov;
    }
    __syncthreads();
}

// ---------------- fused: aggregate + next-layer GEMM ------------------------

__global__ __launch_bounds__(256) void agg_gemm(const uint4* __restrict__ Abf,
                                                const int* __restrict__ csr,
                                                const unsigned* __restrict__ pd2,
                                                const int* __restrict__ perm,
                                                const float* __restrict__ bias,
                                                const unsigned short* __restrict__ Wt,
                                                unsigned short* __restrict__ outb, int N) {
    __shared__ unsigned short sA[16][SP];
    __shared__ int snode[16];
    __shared__ float snrm[16];
    gather_phase(Abf, csr, pd2, perm, bias, sA, snode, snrm, N);

    const int tid = threadIdx.x;
    const int wave = tid >> 6;
    const int l64 = tid & 63;
    const int m = l64 & 15;
    const int quad = l64 >> 4;

    f32x4 acc[2];
    acc[0] = (f32x4){0.f, 0.f, 0.f, 0.f};
    acc[1] = (f32x4){0.f, 0.f, 0.f, 0.f};

#pragma unroll
    for (int kt = 0; kt < 4; ++kt) {
        const int kof = kt * 32 + quad * 8;
        bf16x8 a = *(const bf16x8*)&sA[m][kof];
#pragma unroll
        for (int c2 = 0; c2 < 2; ++c2) {
            const int ct = wave * 2 + c2;
            bf16x8 b = *(const bf16x8*)(Wt + (ct * 16 + m) * DH + kof);
            acc[c2] = __builtin_amdgcn_mfma_f32_16x16x32_bf16(a, b, acc[c2], 0, 0, 0);
        }
    }

#pragma unroll
    for (int reg = 0; reg < 4; ++reg) {
        int idx = blockIdx.x * 16 + quad * 4 + reg;
        if (idx < N) {
            int r = snode[quad * 4 + reg];
            float s = snrm[quad * 4 + reg];
#pragma unroll
            for (int c2 = 0; c2 < 2; ++c2)
                outb[(size_t)r * DH + (wave * 2 + c2) * 16 + m] = f2bf(acc[c2][reg] * s);
        }
    }
}

// ---------------- fused: aggregate + head GEMM + log_softmax ----------------

__global__ __launch_bounds__(256) void agg_head(const uint4* __restrict__ Abf,
                                                const int* __restrict__ csr,
                                                const unsigned* __restrict__ pd2,
                                                const int* __restrict__ perm,
                                                const float* __restrict__ bias,
                                                const unsigned short* __restrict__ Wft,
                                                const float* __restrict__ bfh,
                                                float* __restrict__ out, int N) {
    __shared__ unsigned short sA[16][SP];
    __shared__ int snode[16];
    __shared__ float snrm[16];
    gather_phase(Abf, csr, pd2, perm, bias, sA, snode, snrm, N);

    const int tid = threadIdx.x;
    if (tid >= 64) return;                 // one wave does the 16x48 head
    const int m = tid & 15;
    const int quad = tid >> 4;

    f32x4 acc[3];
#pragma unroll
    for (int ct = 0; ct < 3; ++ct) acc[ct] = (f32x4){0.f, 0.f, 0.f, 0.f};

#pragma unroll
    for (int kt = 0; kt < 4; ++kt) {
        const int kof = kt * 32 + quad * 8;
        bf16x8 a = *(const bf16x8*)&sA[m][kof];
#pragma unroll
        for (int ct = 0; ct < 3; ++ct) {
            bf16x8 b = *(const bf16x8*)(Wft + (ct * 16 + m) * DH + kof);
            acc[ct] = __builtin_amdgcn_mfma_f32_16x16x32_bf16(a, b, acc[ct], 0, 0, 0);
        }
    }

    float bias0 = bfh[m];
    float bias1 = bfh[16 + m];
    float bias2 = bfh[32 + m];

#pragma unroll
    for (int reg = 0; reg < 4; ++reg) {
        float v0 = acc[0][reg] + bias0;
        float v1 = acc[1][reg] + bias1;
        float v2 = (m < 8) ? (acc[2][reg] + bias2) : -1e30f;
        float mx = fmaxf(fmaxf(v0, v1), v2);
#pragma unroll
        for (int dlt = 1; dlt < 16; dlt <<= 1) mx = fmaxf(mx, __shfl_xor(mx, dlt));
        float s = __expf(v0 - mx) + __expf(v1 - mx) + ((m < 8) ? __expf(v2 - mx) : 0.f);
#pragma unroll
        for (int dlt = 1; dlt < 16; dlt <<= 1) s += __shfl_xor(s, dlt);
        float ls = mx + __logf(s);
        int idx = blockIdx.x * 16 + quad * 4 + reg;
        if (idx < N) {
            int r = snode[quad * 4 + reg];
            out[(size_t)r * NC + m] = v0 - ls;
            out[(size_t)r * NC + 16 + m] = v1 - ls;
            if (m < 8) out[(size_t)r * NC + 32 + m] = v2 - ls;
        }
    }
}

// ---------------------------------------------------------------------------

extern "C" void kernel_launch(void* const* d_in, const int* in_sizes, int n_in,
                              void* d_out, int out_size, void* d_ws, size_t ws_size,
                              hipStream_t stream) {
    const float* x   = (const float*)d_in[0];
    const int*   ei  = (const int*)d_in[1];
    const float* W1  = (const float*)d_in[2];
    const float* b1  = (const float*)d_in[3];
    const float* W2  = (const float*)d_in[4];
    const float* b2  = (const float*)d_in[5];
    const float* W3  = (const float*)d_in[6];
    const float* b3  = (const float*)d_in[7];
    const float* Wp1 = (const float*)d_in[8];
    const float* bp1 = (const float*)d_in[9];
    const float* Wp2 = (const float*)d_in[10];
    const float* bp2 = (const float*)d_in[11];
    float* out = (float*)d_out;

    const int N = in_sizes[0] / DH;
    const int E = in_sizes[1] / 2;
    const int* src = ei;
    const int* dst = ei + E;
    const int NB = (N + BN - 1) / BN;

    // workspace carve (all 16B aligned)
    char* w = (char*)d_ws;
    unsigned short* Ab  = (unsigned short*)w; w += (size_t)N * DH * 2;
    unsigned short* Bb  = (unsigned short*)w; w += (size_t)N * DH * 2;
    int*      csr    = (int*)w;      w += (size_t)NB * CAP * 4;
    unsigned* ebuf   = (unsigned*)w; w += (size_t)NB * CAP * 4;
    // ---- zeroed region (one memset): dh + binpos + bpos ----
    unsigned* dh     = (unsigned*)w; w += 256 * 4;
    unsigned* binpos = (unsigned*)w; w += 256 * 4;
    unsigned* bpos   = (unsigned*)w; w += MAXNB * 4;
    // ---- end zeroed region ----
    unsigned* cnt    = (unsigned*)w; w += (size_t)N * 4;
    float*    nrm    = (float*)w;    w += (size_t)N * 4;
    unsigned* offN   = (unsigned*)w; w += (size_t)N * 4;
    unsigned* pd2    = (unsigned*)w; w += (size_t)((N + 31) & ~31) * 4;
    int*      perm   = (int*)w;      w += (size_t)((N + 31) & ~31) * 4;
    unsigned short* Wt  = (unsigned short*)w; w += 3 * DH * DH * 2;
    unsigned short* Wft = (unsigned short*)w; w += 48 * DH * 2;
    float*    bfh    = (float*)w;    w += 64 * 4;

    const int gC = (E + CH - 1) / CH;
    const int gN = (N + 255) / 256;
    const int gP = (NPREP + 255) / 256;
    const int gG = (N + 63) / 64;
    const int gF = (N + 15) / 16;

    hipMemsetAsync(dh, 0, 256 * 4 + 256 * 4 + MAXNB * 4, stream);
    bucket_scatter_prep<<<gC + gP, 256, 0, stream>>>(src, dst, E, bpos, ebuf,
                                                     W1, W2, W3, Wp1, bp1, Wp2, bp2,
                                                     Wt, Wft, bfh, gC);
    bucket_degfill<<<NB, 256, 0, stream>>>(ebuf, bpos, cnt, nrm, offN, dh, csr, N);
    degscat_gemm<<<gG + gN, 256, 0, stream>>>(cnt, N, dh, binpos, offN, perm, pd2,
                                              x, Wt, nrm, Ab, gG);

    agg_gemm<<<gF, 256, 0, stream>>>((const uint4*)Ab, csr, pd2, perm, b1,
                                     Wt + DH * DH, Bb, N);
    agg_gemm<<<gF, 256, 0, stream>>>((const uint4*)Bb, csr, pd2, perm, b2,
                                     Wt + 2 * DH * DH, Ab, N);
    agg_head<<<gF, 256, 0, stream>>>((const uint4*)Ab, csr, pd2, perm, b3,
                                     Wft, bfh, out, N);
}